// Round 2
// baseline (843.679 us; speedup 1.0000x reference)
//
#include <hip/hip_runtime.h>
#include <hip/hip_bf16.h>

#define DIMD 1024
#define NEXP 8
#define NTOK 4096
#define HIDN 4096
#define CAP  4096
#define EXPSTRIDE 4194304L  // HIDN*DIMD elements per expert (same for w1 and w2)

typedef __bf16 bf16;
typedef bf16  bf16x8 __attribute__((ext_vector_type(8)));
typedef bf16  bf16x4 __attribute__((ext_vector_type(4)));
typedef float f32x4  __attribute__((ext_vector_type(4)));

__device__ __forceinline__ void gload16(const void* g, void* l) {
  __builtin_amdgcn_global_load_lds(
      (const __attribute__((address_space(1))) unsigned int*)g,
      (__attribute__((address_space(3))) unsigned int*)l, 16, 0, 0);
}

// ---------------- weight |w| partial sums: grid (128, 16) ----------------
__global__ void k_wsum(const float* __restrict__ w1, const float* __restrict__ w2,
                       float* __restrict__ partials) {
  const int slot = blockIdx.y;   // 0-7: w1 expert, 8-15: w2 expert
  const int b = blockIdx.x;
  const int tid = threadIdx.x;
  const float* src = (slot < 8) ? (w1 + (long)slot * EXPSTRIDE)
                                : (w2 + (long)(slot - 8) * EXPSTRIDE);
  const f32x4* p = (const f32x4*)src;
  float s = 0.f;
  #pragma unroll
  for (int j = 0; j < 32; ++j) {
    f32x4 v = p[(long)b * 8192 + j * 256 + tid];
    s += fabsf(v.x) + fabsf(v.y) + fabsf(v.z) + fabsf(v.w);
  }
  #pragma unroll
  for (int o = 1; o < 64; o <<= 1) s += __shfl_xor(s, o, 64);
  __shared__ float red[4];
  if ((tid & 63) == 0) red[tid >> 6] = s;
  __syncthreads();
  if (tid == 0) partials[slot * 128 + b] = red[0] + red[1] + red[2] + red[3];
}

// ---------------- finalize scales + quantize router weights ----------------
__global__ void k_finalize(const float* __restrict__ partials,
                           const float* __restrict__ wr, const float* __restrict__ wn,
                           float* __restrict__ wmean,
                           bf16* __restrict__ wrq, bf16* __restrict__ wnq) {
  const int tid = threadIdx.x;
  if (tid < 16) {  // deterministic serial sum of 128 partials per tensor
    float s = 0.f;
    for (int j = 0; j < 128; ++j) s += partials[tid * 128 + j];
    wmean[tid] = fmaxf(s * (1.0f / 4194304.0f), 1e-5f);
  }
  float sr = 0.f, sn = 0.f;
  #pragma unroll
  for (int j = 0; j < 32; ++j) {
    sr += fabsf(wr[j * 256 + tid]);
    sn += fabsf(wn[j * 256 + tid]);
  }
  #pragma unroll
  for (int o = 1; o < 64; o <<= 1) {
    sr += __shfl_xor(sr, o, 64);
    sn += __shfl_xor(sn, o, 64);
  }
  __shared__ float red[8];
  if ((tid & 63) == 0) { red[tid >> 6] = sr; red[4 + (tid >> 6)] = sn; }
  __syncthreads();
  if (tid == 0) {
    wmean[16] = fmaxf((red[0] + red[1] + red[2] + red[3]) * (1.0f / 8192.0f), 1e-5f);
    wmean[17] = fmaxf((red[4] + red[5] + red[6] + red[7]) * (1.0f / 8192.0f), 1e-5f);
  }
  __syncthreads();
  const float ir = 1.0f / wmean[16];
  const float in = 1.0f / wmean[17];
  for (int j = 0; j < 32; ++j) {
    int i = j * 256 + tid;
    wrq[i] = (bf16)fminf(fmaxf(rintf(wr[i] * ir), -1.f), 1.f);
    wnq[i] = (bf16)fminf(fmaxf(rintf(wn[i] * in), -1.f), 1.f);
  }
}

// ---------------- ternary-quantize w1/w2 -> bf16 {-1,0,1}: grid 32768 ----------------
__global__ void k_wquant(const float* __restrict__ w1, const float* __restrict__ w2,
                         const float* __restrict__ wmean,
                         bf16* __restrict__ w1q, bf16* __restrict__ w2q) {
  const int tid = threadIdx.x;
  const int which = blockIdx.x >> 14;                       // 0: w1, 1: w2
  const long lg = (long)(blockIdx.x & 16383) * 256 + tid;   // 8-elem group id
  const int e = (int)(lg >> 19);                            // 524288 groups / expert
  const float inv = 1.0f / wmean[(which ? 8 : 0) + e];
  const float* src = which ? w2 : w1;
  bf16* dst = which ? w2q : w1q;
  const f32x4* p = (const f32x4*)src + lg * 2;
  f32x4 v0 = p[0], v1 = p[1];
  bf16x8 q;
  q[0] = (bf16)fminf(fmaxf(rintf(v0.x * inv), -1.f), 1.f);
  q[1] = (bf16)fminf(fmaxf(rintf(v0.y * inv), -1.f), 1.f);
  q[2] = (bf16)fminf(fmaxf(rintf(v0.z * inv), -1.f), 1.f);
  q[3] = (bf16)fminf(fmaxf(rintf(v0.w * inv), -1.f), 1.f);
  q[4] = (bf16)fminf(fmaxf(rintf(v1.x * inv), -1.f), 1.f);
  q[5] = (bf16)fminf(fmaxf(rintf(v1.y * inv), -1.f), 1.f);
  q[6] = (bf16)fminf(fmaxf(rintf(v1.z * inv), -1.f), 1.f);
  q[7] = (bf16)fminf(fmaxf(rintf(v1.w * inv), -1.f), 1.f);
  *(bf16x8*)(dst + lg * 8) = q;
}

// ---------------- x: rmsnorm + int8-grid quant (one block / token) ----------------
__global__ void k_xquant(const float* __restrict__ x, bf16* __restrict__ xq,
                         float* __restrict__ sx) {
  const int t = blockIdx.x, tid = threadIdx.x;
  f32x4 v = ((const f32x4*)(x + (long)t * DIMD))[tid];
  float ss = v.x * v.x + v.y * v.y + v.z * v.z + v.w * v.w;
  float am = fmaxf(fmaxf(fabsf(v.x), fabsf(v.y)), fmaxf(fabsf(v.z), fabsf(v.w)));
  #pragma unroll
  for (int o = 1; o < 64; o <<= 1) {
    ss += __shfl_xor(ss, o, 64);
    am = fmaxf(am, __shfl_xor(am, o, 64));
  }
  __shared__ float red[8];
  if ((tid & 63) == 0) { red[tid >> 6] = ss; red[4 + (tid >> 6)] = am; }
  __syncthreads();
  ss = red[0] + red[1] + red[2] + red[3];
  am = fmaxf(fmaxf(red[4], red[5]), fmaxf(red[6], red[7]));
  const float r = 1.0f / sqrtf(ss * (1.0f / DIMD) + 1e-6f);
  const float amn = fmaxf(am * r, 1e-5f);
  const float s = 127.0f / amn;
  bf16x4 q;
  q[0] = (bf16)fminf(fmaxf(rintf((v.x * r) * s), -128.f), 127.f);
  q[1] = (bf16)fminf(fmaxf(rintf((v.y * r) * s), -128.f), 127.f);
  q[2] = (bf16)fminf(fmaxf(rintf((v.z * r) * s), -128.f), 127.f);
  q[3] = (bf16)fminf(fmaxf(rintf((v.w * r) * s), -128.f), 127.f);
  *(bf16x4*)(xq + (long)t * DIMD + tid * 4) = q;
  if (tid == 0) sx[t] = amn * (1.0f / 127.0f);
}

// ---------------- router: 16 dots + noisy top-2 + gates + compaction ----------------
__global__ void k_router(const bf16* __restrict__ xq, const float* __restrict__ sx,
                         const bf16* __restrict__ wrq, const bf16* __restrict__ wnq,
                         const float* __restrict__ eps, const float* __restrict__ wmean,
                         int* __restrict__ cnt, int* __restrict__ idx,
                         float* __restrict__ gate) {
  __shared__ float xf[DIMD];
  __shared__ float dots[16];
  const int t = blockIdx.x, tid = threadIdx.x;
  const bf16* xr = xq + (long)t * DIMD;
  #pragma unroll
  for (int j = 0; j < 4; ++j) xf[tid * 4 + j] = (float)xr[tid * 4 + j];
  __syncthreads();
  const int grp = tid >> 4, l16 = tid & 15;
  const bf16* wv = (grp < 8) ? (wrq + grp * DIMD) : (wnq + (grp - 8) * DIMD);
  float s = 0.f;
  #pragma unroll
  for (int j = 0; j < 64; ++j) s += xf[l16 + j * 16] * (float)wv[l16 + j * 16];
  s += __shfl_xor(s, 1, 64); s += __shfl_xor(s, 2, 64);
  s += __shfl_xor(s, 4, 64); s += __shfl_xor(s, 8, 64);
  if (l16 == 0) dots[grp] = s;
  __syncthreads();
  if (tid == 0) {
    const float st = sx[t];
    const float fr = st * wmean[16], fn = st * wmean[17];
    float ny[8];
    #pragma unroll
    for (int e = 0; e < 8; ++e) {
      const float nl = dots[8 + e] * fn;
      const float sp = fmaxf(nl, 0.f) + log1pf(expf(-fabsf(nl)));
      ny[e] = dots[e] * fr + eps[t * 8 + e] * sp;
    }
    int i1 = 0;
    #pragma unroll
    for (int e = 1; e < 8; ++e) if (ny[e] > ny[i1]) i1 = e;
    int i2 = (i1 == 0) ? 1 : 0;
    #pragma unroll
    for (int e = 0; e < 8; ++e) if (e != i1 && ny[e] > ny[i2]) i2 = e;
    const float ex = expf(ny[i2] - ny[i1]);
    const float g1 = 1.0f / (1.0f + ex);
    const float g2 = ex * g1;
    int p1 = atomicAdd(&cnt[i1], 1);
    idx[i1 * CAP + p1] = t; gate[i1 * CAP + p1] = g1;
    int p2 = atomicAdd(&cnt[i2], 1);
    idx[i2 * CAP + p2] = t; gate[i2 * CAP + p2] = g2;
  }
}

__global__ void k_offsets(const int* __restrict__ cnt, int* __restrict__ offs) {
  if (threadIdx.x == 0) {
    int a = 0;
    for (int e = 0; e < NEXP; ++e) { offs[e] = a; a += cnt[e]; }
    offs[8] = a;
  }
}

// ---------------- bf16 MFMA GEMM, 128x128 tile, BK=64, XOR-swizzled LDS ----------------
// L1:  h[oe+i][:] = relu( (xq[tok] . w1q[e]) * sx[tok]*wmean[e] )
// !L1: atomicAdd(out[tok][:], (hq[oe+i] . w2q[e]) * sh[oe+i]*wmean[8+e]*gate)
template <int KD, bool L1>
__global__ __launch_bounds__(256) void k_gemm(
    const bf16* __restrict__ Abase, const bf16* __restrict__ Wq,
    const int* __restrict__ cnt, const int* __restrict__ offs,
    const int* __restrict__ idx, const float* __restrict__ gate,
    const float* __restrict__ srow, const float* __restrict__ wmean,
    float* __restrict__ Out) {
  const int e = blockIdx.z, mt = blockIdx.y, nt = blockIdx.x;
  const int c = cnt[e];
  if (mt * 128 >= c) return;
  const int oe = offs[e];
  __shared__ __align__(16) char lds[33280];
  char* lA = lds;
  char* lB = lds + 16384;
  int* tokL = (int*)(lds + 32768);
  const int tid = threadIdx.x, w = tid >> 6, lam = tid & 63;
  if (tid < 128) {
    int i = mt * 128 + tid;
    tokL[tid] = idx[e * CAP + (i < c ? i : c - 1)];
  }
  __syncthreads();

  // per-lane staging sources (4 A rows + 4 B rows, 16B chunks, pre-swizzled)
  const bf16* aP[4];
  const bf16* bP[4];
  #pragma unroll
  for (int i = 0; i < 4; ++i) {
    const int lrow = w * 32 + i * 8 + (lam >> 3);
    const int schunk = (lam & 7) ^ (lrow & 7);
    long arow;
    if (L1) arow = (long)tokL[lrow];
    else { int ii = mt * 128 + lrow; arow = (long)oe + (ii < c ? ii : c - 1); }
    aP[i] = Abase + arow * KD + schunk * 8;
    bP[i] = Wq + (long)e * EXPSTRIDE + (long)(nt * 128 + lrow) * KD + schunk * 8;
  }
  // fragment read offsets (swizzle-matched)
  const int wr = w >> 1, wc = w & 1;
  int offA[4][2], offB[4][2];
  #pragma unroll
  for (int m = 0; m < 4; ++m) {
    const int ra = wr * 64 + m * 16 + (lam & 15);
    const int rb = wc * 64 + m * 16 + (lam & 15);
    #pragma unroll
    for (int ks = 0; ks < 2; ++ks) {
      const int ch = ks * 4 + (lam >> 4);
      offA[m][ks] = ra * 128 + ((ch ^ (ra & 7)) << 4);
      offB[m][ks] = rb * 128 + ((ch ^ (rb & 7)) << 4);
    }
  }
  f32x4 acc[4][4];
  #pragma unroll
  for (int m = 0; m < 4; ++m)
    #pragma unroll
    for (int n = 0; n < 4; ++n) acc[m][n] = (f32x4){0.f, 0.f, 0.f, 0.f};

  const int lbase = (w * 32) * 128 + lam * 16;
  for (int kb = 0; kb < KD / 64; ++kb) {
    #pragma unroll
    for (int i = 0; i < 4; ++i) {
      gload16(aP[i] + kb * 64, lA + lbase + i * 1024);
      gload16(bP[i] + kb * 64, lB + lbase + i * 1024);
    }
    __syncthreads();
    #pragma unroll
    for (int ks = 0; ks < 2; ++ks) {
      bf16x8 af[4], bfr[4];
      #pragma unroll
      for (int m = 0; m < 4; ++m) af[m] = *(const bf16x8*)(lA + offA[m][ks]);
      #pragma unroll
      for (int n = 0; n < 4; ++n) bfr[n] = *(const bf16x8*)(lB + offB[n][ks]);
      #pragma unroll
      for (int m = 0; m < 4; ++m)
        #pragma unroll
        for (int n = 0; n < 4; ++n)
          acc[m][n] = __builtin_amdgcn_mfma_f32_16x16x32_bf16(af[m], bfr[n], acc[m][n], 0, 0, 0);
    }
    __syncthreads();
  }

  const float wm = wmean[(L1 ? 0 : 8) + e];
  #pragma unroll
  for (int m = 0; m < 4; ++m) {
    #pragma unroll
    for (int r = 0; r < 4; ++r) {
      const int rl = wr * 64 + m * 16 + ((lam >> 4) << 2) + r;
      const int i = mt * 128 + rl;
      if (i < c) {
        if (L1) {
          const float fac = srow[tokL[rl]] * wm;
          float* hp = Out + (long)(oe + i) * HIDN + nt * 128 + wc * 64 + (lam & 15);
          #pragma unroll
          for (int n = 0; n < 4; ++n) hp[n * 16] = fmaxf(acc[m][n][r] * fac, 0.f);
        } else {
          const float fac = srow[oe + i] * wm * gate[e * CAP + i];
          float* op = Out + (long)tokL[rl] * DIMD + nt * 128 + wc * 64 + (lam & 15);
          #pragma unroll
          for (int n = 0; n < 4; ++n) atomicAdd(op + n * 16, acc[m][n][r] * fac);
        }
      }
    }
  }
}

// ---------------- h: rmsnorm + int8-grid quant (one block / assignment row) ----------------
__global__ void k_hquant(const float* __restrict__ h, bf16* __restrict__ hq,
                         float* __restrict__ sh, const int* __restrict__ offs) {
  const int row = blockIdx.x;
  if (row >= offs[8]) return;
  const int tid = threadIdx.x;
  const f32x4* hr = (const f32x4*)(h + (long)row * HIDN);
  f32x4 v[4];
  float ss = 0.f, am = 0.f;
  #pragma unroll
  for (int j = 0; j < 4; ++j) {
    v[j] = hr[tid + j * 256];
    ss += v[j].x * v[j].x + v[j].y * v[j].y + v[j].z * v[j].z + v[j].w * v[j].w;
    am = fmaxf(am, fmaxf(fmaxf(fabsf(v[j].x), fabsf(v[j].y)),
                         fmaxf(fabsf(v[j].z), fabsf(v[j].w))));
  }
  #pragma unroll
  for (int o = 1; o < 64; o <<= 1) {
    ss += __shfl_xor(ss, o, 64);
    am = fmaxf(am, __shfl_xor(am, o, 64));
  }
  __shared__ float red[8];
  if ((tid & 63) == 0) { red[tid >> 6] = ss; red[4 + (tid >> 6)] = am; }
  __syncthreads();
  ss = red[0] + red[1] + red[2] + red[3];
  am = fmaxf(fmaxf(red[4], red[5]), fmaxf(red[6], red[7]));
  const float r = 1.0f / sqrtf(ss * (1.0f / HIDN) + 1e-6f);
  const float amn = fmaxf(am * r, 1e-5f);
  const float s = 127.0f / amn;
  bf16* dst = hq + (long)row * HIDN;
  #pragma unroll
  for (int j = 0; j < 4; ++j) {
    bf16x4 q;
    q[0] = (bf16)fminf(fmaxf(rintf((v[j].x * r) * s), -128.f), 127.f);
    q[1] = (bf16)fminf(fmaxf(rintf((v[j].y * r) * s), -128.f), 127.f);
    q[2] = (bf16)fminf(fmaxf(rintf((v[j].z * r) * s), -128.f), 127.f);
    q[3] = (bf16)fminf(fmaxf(rintf((v[j].w * r) * s), -128.f), 127.f);
    *(bf16x4*)(dst + (tid + j * 256) * 4) = q;
  }
  if (tid == 0) sh[row] = amn * (1.0f / 127.0f);
}

extern "C" void kernel_launch(void* const* d_in, const int* in_sizes, int n_in,
                              void* d_out, int out_size, void* d_ws, size_t ws_size,
                              hipStream_t stream) {
  const float* x   = (const float*)d_in[0];
  const float* eps = (const float*)d_in[1];
  const float* wr  = (const float*)d_in[2];
  const float* wn  = (const float*)d_in[3];
  const float* w1  = (const float*)d_in[4];
  const float* w2  = (const float*)d_in[5];
  float* out = (float*)d_out;
  (void)in_sizes; (void)n_in; (void)ws_size;

  char* ws = (char*)d_ws;
  size_t off = 0;
  auto alloc = [&](size_t bytes) -> void* {
    void* p = ws + off;
    off = (off + bytes + 255) & ~(size_t)255;
    return p;
  };
  bf16*  w1q      = (bf16*)alloc(67108864);
  bf16*  w2q      = (bf16*)alloc(67108864);
  bf16*  wrq      = (bf16*)alloc(16384);
  bf16*  wnq      = (bf16*)alloc(16384);
  bf16*  xq       = (bf16*)alloc(8388608);
  float* sx       = (float*)alloc(16384);
  float* sh       = (float*)alloc(32768);
  int*   idxb     = (int*)alloc(131072);
  float* gateb    = (float*)alloc(131072);
  int*   cntb     = (int*)alloc(64);
  int*   offsb    = (int*)alloc(64);
  float* partials = (float*)alloc(8192);
  float* wmean    = (float*)alloc(128);
  float* h        = (float*)alloc(134217728);
  bf16*  hq       = (bf16*)alloc(67108864);

  hipMemsetAsync(out, 0, (size_t)out_size * sizeof(float), stream);
  hipMemsetAsync(cntb, 0, 64, stream);

  k_wsum<<<dim3(128, 16), 256, 0, stream>>>(w1, w2, partials);
  k_finalize<<<1, 256, 0, stream>>>(partials, wr, wn, wmean, wrq, wnq);
  k_wquant<<<32768, 256, 0, stream>>>(w1, w2, wmean, w1q, w2q);
  k_xquant<<<NTOK, 256, 0, stream>>>(x, xq, sx);
  k_router<<<NTOK, 256, 0, stream>>>(xq, sx, wrq, wnq, eps, wmean, cntb, idxb, gateb);
  k_offsets<<<1, 64, 0, stream>>>(cntb, offsb);
  k_gemm<1024, true><<<dim3(32, 32, 8), 256, 0, stream>>>(
      xq, w1q, cntb, offsb, idxb, gateb, sx, wmean, h);
  k_hquant<<<8192, 256, 0, stream>>>(h, hq, sh, offsb);
  k_gemm<4096, false><<<dim3(8, 32, 8), 256, 0, stream>>>(
      hq, w2q, cntb, offsb, idxb, gateb, sh, wmean, out);
}

// Round 3
// 762.027 us; speedup vs baseline: 1.1072x; 1.1072x over previous
//
#include <hip/hip_runtime.h>
#include <hip/hip_bf16.h>

#define DIMD 1024
#define NEXP 8
#define NTOK 4096
#define HIDN 4096
#define CAP  4096
#define EXPSTRIDE 4194304L  // HIDN*DIMD elements per expert (same for w1 and w2)

typedef __bf16 bf16;
typedef bf16  bf16x8 __attribute__((ext_vector_type(8)));
typedef bf16  bf16x4 __attribute__((ext_vector_type(4)));
typedef float f32x4  __attribute__((ext_vector_type(4)));

__device__ __forceinline__ void gload16(const void* g, void* l) {
  __builtin_amdgcn_global_load_lds(
      (const __attribute__((address_space(1))) unsigned int*)g,
      (__attribute__((address_space(3))) unsigned int*)l, 16, 0, 0);
}

#define VMCNT8 asm volatile("s_waitcnt vmcnt(8)" ::: "memory")
#define VMCNT0 asm volatile("s_waitcnt vmcnt(0)" ::: "memory")
#define BAR    __builtin_amdgcn_s_barrier()

// ---------------- weight |w| partial sums: grid (128, 16) ----------------
__global__ void k_wsum(const float* __restrict__ w1, const float* __restrict__ w2,
                       float* __restrict__ partials) {
  const int slot = blockIdx.y;   // 0-7: w1 expert, 8-15: w2 expert
  const int b = blockIdx.x;
  const int tid = threadIdx.x;
  const float* src = (slot < 8) ? (w1 + (long)slot * EXPSTRIDE)
                                : (w2 + (long)(slot - 8) * EXPSTRIDE);
  const f32x4* p = (const f32x4*)src;
  float s = 0.f;
  #pragma unroll
  for (int j = 0; j < 32; ++j) {
    f32x4 v = p[(long)b * 8192 + j * 256 + tid];
    s += fabsf(v.x) + fabsf(v.y) + fabsf(v.z) + fabsf(v.w);
  }
  #pragma unroll
  for (int o = 1; o < 64; o <<= 1) s += __shfl_xor(s, o, 64);
  __shared__ float red[4];
  if ((tid & 63) == 0) red[tid >> 6] = s;
  __syncthreads();
  if (tid == 0) partials[slot * 128 + b] = red[0] + red[1] + red[2] + red[3];
}

// ---------------- finalize scales + quantize router weights ----------------
__global__ void k_finalize(const float* __restrict__ partials,
                           const float* __restrict__ wr, const float* __restrict__ wn,
                           float* __restrict__ wmean,
                           bf16* __restrict__ wrq, bf16* __restrict__ wnq) {
  const int tid = threadIdx.x;
  if (tid < 16) {  // deterministic serial sum of 128 partials per tensor
    float s = 0.f;
    for (int j = 0; j < 128; ++j) s += partials[tid * 128 + j];
    wmean[tid] = fmaxf(s * (1.0f / 4194304.0f), 1e-5f);
  }
  float sr = 0.f, sn = 0.f;
  #pragma unroll
  for (int j = 0; j < 32; ++j) {
    sr += fabsf(wr[j * 256 + tid]);
    sn += fabsf(wn[j * 256 + tid]);
  }
  #pragma unroll
  for (int o = 1; o < 64; o <<= 1) {
    sr += __shfl_xor(sr, o, 64);
    sn += __shfl_xor(sn, o, 64);
  }
  __shared__ float red[8];
  if ((tid & 63) == 0) { red[tid >> 6] = sr; red[4 + (tid >> 6)] = sn; }
  __syncthreads();
  if (tid == 0) {
    wmean[16] = fmaxf((red[0] + red[1] + red[2] + red[3]) * (1.0f / 8192.0f), 1e-5f);
    wmean[17] = fmaxf((red[4] + red[5] + red[6] + red[7]) * (1.0f / 8192.0f), 1e-5f);
  }
  __syncthreads();
  const float ir = 1.0f / wmean[16];
  const float in = 1.0f / wmean[17];
  for (int j = 0; j < 32; ++j) {
    int i = j * 256 + tid;
    wrq[i] = (bf16)fminf(fmaxf(rintf(wr[i] * ir), -1.f), 1.f);
    wnq[i] = (bf16)fminf(fmaxf(rintf(wn[i] * in), -1.f), 1.f);
  }
}

// ---------------- ternary-quantize w1/w2 -> bf16 {-1,0,1}: grid 32768 ----------------
__global__ void k_wquant(const float* __restrict__ w1, const float* __restrict__ w2,
                         const float* __restrict__ wmean,
                         bf16* __restrict__ w1q, bf16* __restrict__ w2q) {
  const int tid = threadIdx.x;
  const int which = blockIdx.x >> 14;                       // 0: w1, 1: w2
  const long lg = (long)(blockIdx.x & 16383) * 256 + tid;   // 8-elem group id
  const int e = (int)(lg >> 19);                            // 524288 groups / expert
  const float inv = 1.0f / wmean[(which ? 8 : 0) + e];
  const float* src = which ? w2 : w1;
  bf16* dst = which ? w2q : w1q;
  const f32x4* p = (const f32x4*)src + lg * 2;
  f32x4 v0 = p[0], v1 = p[1];
  bf16x8 q;
  q[0] = (bf16)fminf(fmaxf(rintf(v0.x * inv), -1.f), 1.f);
  q[1] = (bf16)fminf(fmaxf(rintf(v0.y * inv), -1.f), 1.f);
  q[2] = (bf16)fminf(fmaxf(rintf(v0.z * inv), -1.f), 1.f);
  q[3] = (bf16)fminf(fmaxf(rintf(v0.w * inv), -1.f), 1.f);
  q[4] = (bf16)fminf(fmaxf(rintf(v1.x * inv), -1.f), 1.f);
  q[5] = (bf16)fminf(fmaxf(rintf(v1.y * inv), -1.f), 1.f);
  q[6] = (bf16)fminf(fmaxf(rintf(v1.z * inv), -1.f), 1.f);
  q[7] = (bf16)fminf(fmaxf(rintf(v1.w * inv), -1.f), 1.f);
  *(bf16x8*)(dst + lg * 8) = q;
}

// ---------------- x: rmsnorm + int8-grid quant (one block / token) ----------------
__global__ void k_xquant(const float* __restrict__ x, bf16* __restrict__ xq,
                         float* __restrict__ sx) {
  const int t = blockIdx.x, tid = threadIdx.x;
  f32x4 v = ((const f32x4*)(x + (long)t * DIMD))[tid];
  float ss = v.x * v.x + v.y * v.y + v.z * v.z + v.w * v.w;
  float am = fmaxf(fmaxf(fabsf(v.x), fabsf(v.y)), fmaxf(fabsf(v.z), fabsf(v.w)));
  #pragma unroll
  for (int o = 1; o < 64; o <<= 1) {
    ss += __shfl_xor(ss, o, 64);
    am = fmaxf(am, __shfl_xor(am, o, 64));
  }
  __shared__ float red[8];
  if ((tid & 63) == 0) { red[tid >> 6] = ss; red[4 + (tid >> 6)] = am; }
  __syncthreads();
  ss = red[0] + red[1] + red[2] + red[3];
  am = fmaxf(fmaxf(red[4], red[5]), fmaxf(red[6], red[7]));
  const float r = 1.0f / sqrtf(ss * (1.0f / DIMD) + 1e-6f);
  const float amn = fmaxf(am * r, 1e-5f);
  const float s = 127.0f / amn;
  bf16x4 q;
  q[0] = (bf16)fminf(fmaxf(rintf((v.x * r) * s), -128.f), 127.f);
  q[1] = (bf16)fminf(fmaxf(rintf((v.y * r) * s), -128.f), 127.f);
  q[2] = (bf16)fminf(fmaxf(rintf((v.z * r) * s), -128.f), 127.f);
  q[3] = (bf16)fminf(fmaxf(rintf((v.w * r) * s), -128.f), 127.f);
  *(bf16x4*)(xq + (long)t * DIMD + tid * 4) = q;
  if (tid == 0) sx[t] = amn * (1.0f / 127.0f);
}

// ---------------- router: 16 dots + noisy top-2 + gates + compaction ----------------
__global__ void k_router(const bf16* __restrict__ xq, const float* __restrict__ sx,
                         const bf16* __restrict__ wrq, const bf16* __restrict__ wnq,
                         const float* __restrict__ eps, const float* __restrict__ wmean,
                         int* __restrict__ cnt, int* __restrict__ idx,
                         float* __restrict__ gate) {
  __shared__ float xf[DIMD];
  __shared__ float dots[16];
  const int t = blockIdx.x, tid = threadIdx.x;
  const bf16* xr = xq + (long)t * DIMD;
  #pragma unroll
  for (int j = 0; j < 4; ++j) xf[tid * 4 + j] = (float)xr[tid * 4 + j];
  __syncthreads();
  const int grp = tid >> 4, l16 = tid & 15;
  const bf16* wv = (grp < 8) ? (wrq + grp * DIMD) : (wnq + (grp - 8) * DIMD);
  float s = 0.f;
  #pragma unroll
  for (int j = 0; j < 64; ++j) s += xf[l16 + j * 16] * (float)wv[l16 + j * 16];
  s += __shfl_xor(s, 1, 64); s += __shfl_xor(s, 2, 64);
  s += __shfl_xor(s, 4, 64); s += __shfl_xor(s, 8, 64);
  if (l16 == 0) dots[grp] = s;
  __syncthreads();
  if (tid == 0) {
    const float st = sx[t];
    const float fr = st * wmean[16], fn = st * wmean[17];
    float ny[8];
    #pragma unroll
    for (int e = 0; e < 8; ++e) {
      const float nl = dots[8 + e] * fn;
      const float sp = fmaxf(nl, 0.f) + log1pf(expf(-fabsf(nl)));
      ny[e] = dots[e] * fr + eps[t * 8 + e] * sp;
    }
    int i1 = 0;
    #pragma unroll
    for (int e = 1; e < 8; ++e) if (ny[e] > ny[i1]) i1 = e;
    int i2 = (i1 == 0) ? 1 : 0;
    #pragma unroll
    for (int e = 0; e < 8; ++e) if (e != i1 && ny[e] > ny[i2]) i2 = e;
    const float ex = expf(ny[i2] - ny[i1]);
    const float g1 = 1.0f / (1.0f + ex);
    const float g2 = ex * g1;
    int p1 = atomicAdd(&cnt[i1], 1);
    idx[i1 * CAP + p1] = t; gate[i1 * CAP + p1] = g1;
    int p2 = atomicAdd(&cnt[i2], 1);
    idx[i2 * CAP + p2] = t; gate[i2 * CAP + p2] = g2;
  }
}

__global__ void k_offsets(const int* __restrict__ cnt, int* __restrict__ offs) {
  if (threadIdx.x == 0) {
    int a = 0;
    for (int e = 0; e < NEXP; ++e) { offs[e] = a; a += cnt[e]; }
    offs[8] = a;
  }
}

// ---------------- bf16 MFMA GEMM, 128x128 tile, BK=64, XOR-swizzled LDS ----------------
// Double-buffered (T3 min-2-phase: counted vmcnt, raw s_barrier), XCD-aware decode (T1).
// 1-D grid = (NEXP << LOGNT) * 32 blocks; xcd = bid&7 owns pairs {pidx : pidx%8==xcd},
// mt iterates fastest within a pair -> B-tile reused from that XCD's L2.
// L1:  h[oe+i][:] = relu( (xq[tok] . w1q[e]) * sx[tok]*wmean[e] )
// !L1: atomicAdd(out[tok][:], (hq[oe+i] . w2q[e]) * sh[oe+i]*wmean[8+e]*gate)
template <int KD, int LOGNT, bool L1>
__global__ __launch_bounds__(256, 2) void k_gemm(
    const bf16* __restrict__ Abase, const bf16* __restrict__ Wq,
    const int* __restrict__ cnt, const int* __restrict__ offs,
    const int* __restrict__ idx, const float* __restrict__ gate,
    const float* __restrict__ srow, const float* __restrict__ wmean,
    float* __restrict__ Out) {
  const int bid = blockIdx.x;
  const int xcd = bid & 7;
  const int s = bid >> 3;
  const int pl = s >> 5;                     // pair-local index within this XCD
  const int mt = s & 31;                     // mt fastest -> B-tile L2 reuse
  const int pidx = pl * 8 + xcd;             // bijective pair id
  const int e = pidx >> LOGNT;
  const int nt = pidx & ((1 << LOGNT) - 1);

  const int c = cnt[e];
  if (mt * 128 >= c) return;
  const int oe = offs[e];
  __shared__ __align__(16) char lds[66048];
  char* lA0 = lds;
  char* lB0 = lds + 16384;
  char* lA1 = lds + 32768;
  char* lB1 = lds + 49152;
  int* tokL = (int*)(lds + 65536);
  const int tid = threadIdx.x, w = tid >> 6, lam = tid & 63;
  if (tid < 128) {
    int i = mt * 128 + tid;
    tokL[tid] = idx[e * CAP + (i < c ? i : c - 1)];
  }
  __syncthreads();

  // per-lane staging sources (4 A rows + 4 B rows, 16B chunks, pre-swizzled)
  const bf16* aP[4];
  const bf16* bP[4];
  #pragma unroll
  for (int i = 0; i < 4; ++i) {
    const int lrow = w * 32 + i * 8 + (lam >> 3);
    const int schunk = (lam & 7) ^ (lrow & 7);
    long arow;
    if (L1) arow = (long)tokL[lrow];
    else { int ii = mt * 128 + lrow; arow = (long)oe + (ii < c ? ii : c - 1); }
    aP[i] = Abase + arow * KD + schunk * 8;
    bP[i] = Wq + (long)e * EXPSTRIDE + (long)(nt * 128 + lrow) * KD + schunk * 8;
  }
  const int lbase = (w * 32) * 128 + lam * 16;

  auto STAGE = [&](int kb, char* dA, char* dB) {
    #pragma unroll
    for (int i = 0; i < 4; ++i) {
      gload16(aP[i] + kb * 64, dA + lbase + i * 1024);
      gload16(bP[i] + kb * 64, dB + lbase + i * 1024);
    }
  };

  // fragment read offsets (swizzle-matched)
  const int wr = w >> 1, wc = w & 1;
  int offA[4][2], offB[4][2];
  #pragma unroll
  for (int m = 0; m < 4; ++m) {
    const int ra = wr * 64 + m * 16 + (lam & 15);
    const int rb = wc * 64 + m * 16 + (lam & 15);
    #pragma unroll
    for (int ks = 0; ks < 2; ++ks) {
      const int ch = ks * 4 + (lam >> 4);
      offA[m][ks] = ra * 128 + ((ch ^ (ra & 7)) << 4);
      offB[m][ks] = rb * 128 + ((ch ^ (rb & 7)) << 4);
    }
  }
  f32x4 acc[4][4];
  #pragma unroll
  for (int m = 0; m < 4; ++m)
    #pragma unroll
    for (int n = 0; n < 4; ++n) acc[m][n] = (f32x4){0.f, 0.f, 0.f, 0.f};

  auto COMPUTE = [&](const char* cA, const char* cB) {
    #pragma unroll
    for (int ks = 0; ks < 2; ++ks) {
      bf16x8 af[4], bfr[4];
      #pragma unroll
      for (int m = 0; m < 4; ++m) af[m] = *(const bf16x8*)(cA + offA[m][ks]);
      #pragma unroll
      for (int n = 0; n < 4; ++n) bfr[n] = *(const bf16x8*)(cB + offB[n][ks]);
      #pragma unroll
      for (int m = 0; m < 4; ++m)
        #pragma unroll
        for (int n = 0; n < 4; ++n)
          acc[m][n] = __builtin_amdgcn_mfma_f32_16x16x32_bf16(af[m], bfr[n], acc[m][n], 0, 0, 0);
    }
  };

  // K loop: KT even (16 or 64). Prefetch next tile before computing current;
  // counted vmcnt keeps prefetch in flight across the barrier (never drain mid-loop).
  constexpr int KT = KD / 64;
  STAGE(0, lA0, lB0);
  for (int kb = 0; kb < KT; kb += 2) {
    STAGE(kb + 1, lA1, lB1);
    VMCNT8;                 // wait tile kb only; tile kb+1 stays in flight
    BAR;
    COMPUTE(lA0, lB0);
    BAR;                    // all waves done reading buf0 -> safe to overwrite
    if (kb + 2 < KT) { STAGE(kb + 2, lA0, lB0); VMCNT8; } else { VMCNT0; }
    BAR;
    COMPUTE(lA1, lB1);
    BAR;
  }

  const float wm = wmean[(L1 ? 0 : 8) + e];
  #pragma unroll
  for (int m = 0; m < 4; ++m) {
    #pragma unroll
    for (int r = 0; r < 4; ++r) {
      const int rl = wr * 64 + m * 16 + ((lam >> 4) << 2) + r;
      const int i = mt * 128 + rl;
      if (i < c) {
        if (L1) {
          const float fac = srow[tokL[rl]] * wm;
          float* hp = Out + (long)(oe + i) * HIDN + nt * 128 + wc * 64 + (lam & 15);
          #pragma unroll
          for (int n = 0; n < 4; ++n) hp[n * 16] = fmaxf(acc[m][n][r] * fac, 0.f);
        } else {
          const float fac = srow[oe + i] * wm * gate[e * CAP + i];
          float* op = Out + (long)tokL[rl] * DIMD + nt * 128 + wc * 64 + (lam & 15);
          #pragma unroll
          for (int n = 0; n < 4; ++n) atomicAdd(op + n * 16, acc[m][n][r] * fac);
        }
      }
    }
  }
}

// ---------------- h: rmsnorm + int8-grid quant (one block / assignment row) ----------------
__global__ void k_hquant(const float* __restrict__ h, bf16* __restrict__ hq,
                         float* __restrict__ sh, const int* __restrict__ offs) {
  const int row = blockIdx.x;
  if (row >= offs[8]) return;
  const int tid = threadIdx.x;
  const f32x4* hr = (const f32x4*)(h + (long)row * HIDN);
  f32x4 v[4];
  float ss = 0.f, am = 0.f;
  #pragma unroll
  for (int j = 0; j < 4; ++j) {
    v[j] = hr[tid + j * 256];
    ss += v[j].x * v[j].x + v[j].y * v[j].y + v[j].z * v[j].z + v[j].w * v[j].w;
    am = fmaxf(am, fmaxf(fmaxf(fabsf(v[j].x), fabsf(v[j].y)),
                         fmaxf(fabsf(v[j].z), fabsf(v[j].w))));
  }
  #pragma unroll
  for (int o = 1; o < 64; o <<= 1) {
    ss += __shfl_xor(ss, o, 64);
    am = fmaxf(am, __shfl_xor(am, o, 64));
  }
  __shared__ float red[8];
  if ((tid & 63) == 0) { red[tid >> 6] = ss; red[4 + (tid >> 6)] = am; }
  __syncthreads();
  ss = red[0] + red[1] + red[2] + red[3];
  am = fmaxf(fmaxf(red[4], red[5]), fmaxf(red[6], red[7]));
  const float r = 1.0f / sqrtf(ss * (1.0f / HIDN) + 1e-6f);
  const float amn = fmaxf(am * r, 1e-5f);
  const float s = 127.0f / amn;
  bf16* dst = hq + (long)row * HIDN;
  #pragma unroll
  for (int j = 0; j < 4; ++j) {
    bf16x4 q;
    q[0] = (bf16)fminf(fmaxf(rintf((v[j].x * r) * s), -128.f), 127.f);
    q[1] = (bf16)fminf(fmaxf(rintf((v[j].y * r) * s), -128.f), 127.f);
    q[2] = (bf16)fminf(fmaxf(rintf((v[j].z * r) * s), -128.f), 127.f);
    q[3] = (bf16)fminf(fmaxf(rintf((v[j].w * r) * s), -128.f), 127.f);
    *(bf16x4*)(dst + (tid + j * 256) * 4) = q;
  }
  if (tid == 0) sh[row] = amn * (1.0f / 127.0f);
}

extern "C" void kernel_launch(void* const* d_in, const int* in_sizes, int n_in,
                              void* d_out, int out_size, void* d_ws, size_t ws_size,
                              hipStream_t stream) {
  const float* x   = (const float*)d_in[0];
  const float* eps = (const float*)d_in[1];
  const float* wr  = (const float*)d_in[2];
  const float* wn  = (const float*)d_in[3];
  const float* w1  = (const float*)d_in[4];
  const float* w2  = (const float*)d_in[5];
  float* out = (float*)d_out;
  (void)in_sizes; (void)n_in; (void)ws_size;

  char* ws = (char*)d_ws;
  size_t off = 0;
  auto alloc = [&](size_t bytes) -> void* {
    void* p = ws + off;
    off = (off + bytes + 255) & ~(size_t)255;
    return p;
  };
  bf16*  w1q      = (bf16*)alloc(67108864);
  bf16*  w2q      = (bf16*)alloc(67108864);
  bf16*  wrq      = (bf16*)alloc(16384);
  bf16*  wnq      = (bf16*)alloc(16384);
  bf16*  xq       = (bf16*)alloc(8388608);
  float* sx       = (float*)alloc(16384);
  float* sh       = (float*)alloc(32768);
  int*   idxb     = (int*)alloc(131072);
  float* gateb    = (float*)alloc(131072);
  int*   cntb     = (int*)alloc(64);
  int*   offsb    = (int*)alloc(64);
  float* partials = (float*)alloc(8192);
  float* wmean    = (float*)alloc(128);
  float* h        = (float*)alloc(134217728);
  bf16*  hq       = (bf16*)alloc(67108864);

  hipMemsetAsync(out, 0, (size_t)out_size * sizeof(float), stream);
  hipMemsetAsync(cntb, 0, 64, stream);

  k_wsum<<<dim3(128, 16), 256, 0, stream>>>(w1, w2, partials);
  k_finalize<<<1, 256, 0, stream>>>(partials, wr, wn, wmean, wrq, wnq);
  k_wquant<<<32768, 256, 0, stream>>>(w1, w2, wmean, w1q, w2q);
  k_xquant<<<NTOK, 256, 0, stream>>>(x, xq, sx);
  k_router<<<NTOK, 256, 0, stream>>>(xq, sx, wrq, wnq, eps, wmean, cntb, idxb, gateb);
  k_offsets<<<1, 64, 0, stream>>>(cntb, offsb);
  k_gemm<1024, 5, true><<<8192, 256, 0, stream>>>(
      xq, w1q, cntb, offsb, idxb, gateb, sx, wmean, h);
  k_hquant<<<8192, 256, 0, stream>>>(h, hq, sh, offsb);
  k_gemm<4096, 3, false><<<2048, 256, 0, stream>>>(
      hq, w2q, cntb, offsb, idxb, gateb, sh, wmean, out);
}

// Round 9
// 661.296 us; speedup vs baseline: 1.2758x; 1.1523x over previous
//
#include <hip/hip_runtime.h>
#include <hip/hip_bf16.h>

#define DIMD 1024
#define NEXP 8
#define NTOK 4096
#define HIDN 4096
#define CAP  4096
#define EXPSTRIDE 4194304L  // HIDN*DIMD bytes per expert (i8)

typedef __bf16 bf16;
typedef bf16  bf16x8 __attribute__((ext_vector_type(8)));
typedef float f32x4  __attribute__((ext_vector_type(4)));
typedef int   i32x4  __attribute__((ext_vector_type(4)));
typedef signed char i8x8 __attribute__((ext_vector_type(8)));
typedef signed char i8x4 __attribute__((ext_vector_type(4)));
typedef signed char i8;

__device__ __forceinline__ void gload16(const void* g, void* l) {
  __builtin_amdgcn_global_load_lds(
      (const __attribute__((address_space(1))) unsigned int*)g,
      (__attribute__((address_space(3))) unsigned int*)l, 16, 0, 0);
}

#define VMCNT4 asm volatile("s_waitcnt vmcnt(4)" ::: "memory")
#define VMCNT0 asm volatile("s_waitcnt vmcnt(0)" ::: "memory")
// Raw s_barrier WITH compiler memory fence: __builtin_amdgcn_s_barrier() has no
// memory-ordering semantics at IR level, so LLVM could hoist LDS reads above the
// barrier (race: wave A reads chunks wave B's global_load_lds hasn't landed).
// The asm memory clobber pins all memory ops; emits the same single instruction.
#define BAR    asm volatile("s_barrier" ::: "memory")

// ---------------- weight |w| partial sums: grid (128, 16) ----------------
__global__ void k_wsum(const float* __restrict__ w1, const float* __restrict__ w2,
                       float* __restrict__ partials) {
  const int slot = blockIdx.y;   // 0-7: w1 expert, 8-15: w2 expert
  const int b = blockIdx.x;
  const int tid = threadIdx.x;
  const float* src = (slot < 8) ? (w1 + (long)slot * EXPSTRIDE)
                                : (w2 + (long)(slot - 8) * EXPSTRIDE);
  const f32x4* p = (const f32x4*)src;
  float s = 0.f;
  #pragma unroll
  for (int j = 0; j < 32; ++j) {
    f32x4 v = p[(long)b * 8192 + j * 256 + tid];
    s += fabsf(v.x) + fabsf(v.y) + fabsf(v.z) + fabsf(v.w);
  }
  #pragma unroll
  for (int o = 1; o < 64; o <<= 1) s += __shfl_xor(s, o, 64);
  __shared__ float red[4];
  if ((tid & 63) == 0) red[tid >> 6] = s;
  __syncthreads();
  if (tid == 0) partials[slot * 128 + b] = red[0] + red[1] + red[2] + red[3];
}

// ---------------- finalize scales + quantize router weights ----------------
__global__ void k_finalize(const float* __restrict__ partials,
                           const float* __restrict__ wr, const float* __restrict__ wn,
                           float* __restrict__ wmean,
                           bf16* __restrict__ wrq, bf16* __restrict__ wnq) {
  const int tid = threadIdx.x;
  if (tid < 16) {  // deterministic serial sum of 128 partials per tensor
    float s = 0.f;
    for (int j = 0; j < 128; ++j) s += partials[tid * 128 + j];
    wmean[tid] = fmaxf(s * (1.0f / 4194304.0f), 1e-5f);
  }
  float sr = 0.f, sn = 0.f;
  #pragma unroll
  for (int j = 0; j < 32; ++j) {
    sr += fabsf(wr[j * 256 + tid]);
    sn += fabsf(wn[j * 256 + tid]);
  }
  #pragma unroll
  for (int o = 1; o < 64; o <<= 1) {
    sr += __shfl_xor(sr, o, 64);
    sn += __shfl_xor(sn, o, 64);
  }
  __shared__ float red[8];
  if ((tid & 63) == 0) { red[tid >> 6] = sr; red[4 + (tid >> 6)] = sn; }
  __syncthreads();
  if (tid == 0) {
    wmean[16] = fmaxf((red[0] + red[1] + red[2] + red[3]) * (1.0f / 8192.0f), 1e-5f);
    wmean[17] = fmaxf((red[4] + red[5] + red[6] + red[7]) * (1.0f / 8192.0f), 1e-5f);
  }
  __syncthreads();
  const float ir = 1.0f / wmean[16];
  const float in = 1.0f / wmean[17];
  for (int j = 0; j < 32; ++j) {
    int i = j * 256 + tid;
    wrq[i] = (bf16)fminf(fmaxf(rintf(wr[i] * ir), -1.f), 1.f);
    wnq[i] = (bf16)fminf(fmaxf(rintf(wn[i] * in), -1.f), 1.f);
  }
}

// ---------------- ternary-quantize w1/w2 -> i8 {-1,0,1}: grid 32768 ----------------
__global__ void k_wquant(const float* __restrict__ w1, const float* __restrict__ w2,
                         const float* __restrict__ wmean,
                         i8* __restrict__ w1q, i8* __restrict__ w2q) {
  const int tid = threadIdx.x;
  const int which = blockIdx.x >> 14;                       // 0: w1, 1: w2
  const long lg = (long)(blockIdx.x & 16383) * 256 + tid;   // 8-elem group id
  const int e = (int)(lg >> 19);                            // 524288 groups / expert
  const float inv = 1.0f / wmean[(which ? 8 : 0) + e];
  const float* src = which ? w2 : w1;
  i8* dst = which ? w2q : w1q;
  const f32x4* p = (const f32x4*)src + lg * 2;
  f32x4 v0 = p[0], v1 = p[1];
  i8x8 q;
  q[0] = (i8)fminf(fmaxf(rintf(v0.x * inv), -1.f), 1.f);
  q[1] = (i8)fminf(fmaxf(rintf(v0.y * inv), -1.f), 1.f);
  q[2] = (i8)fminf(fmaxf(rintf(v0.z * inv), -1.f), 1.f);
  q[3] = (i8)fminf(fmaxf(rintf(v0.w * inv), -1.f), 1.f);
  q[4] = (i8)fminf(fmaxf(rintf(v1.x * inv), -1.f), 1.f);
  q[5] = (i8)fminf(fmaxf(rintf(v1.y * inv), -1.f), 1.f);
  q[6] = (i8)fminf(fmaxf(rintf(v1.z * inv), -1.f), 1.f);
  q[7] = (i8)fminf(fmaxf(rintf(v1.w * inv), -1.f), 1.f);
  *(i8x8*)(dst + lg * 8) = q;
}

// ---------------- x: rmsnorm + int8 quant (one block / token) ----------------
__global__ void k_xquant(const float* __restrict__ x, i8* __restrict__ xq,
                         float* __restrict__ sx) {
  const int t = blockIdx.x, tid = threadIdx.x;
  f32x4 v = ((const f32x4*)(x + (long)t * DIMD))[tid];
  float ss = v.x * v.x + v.y * v.y + v.z * v.z + v.w * v.w;
  float am = fmaxf(fmaxf(fabsf(v.x), fabsf(v.y)), fmaxf(fabsf(v.z), fabsf(v.w)));
  #pragma unroll
  for (int o = 1; o < 64; o <<= 1) {
    ss += __shfl_xor(ss, o, 64);
    am = fmaxf(am, __shfl_xor(am, o, 64));
  }
  __shared__ float red[8];
  if ((tid & 63) == 0) { red[tid >> 6] = ss; red[4 + (tid >> 6)] = am; }
  __syncthreads();
  ss = red[0] + red[1] + red[2] + red[3];
  am = fmaxf(fmaxf(red[4], red[5]), fmaxf(red[6], red[7]));
  const float r = 1.0f / sqrtf(ss * (1.0f / DIMD) + 1e-6f);
  const float amn = fmaxf(am * r, 1e-5f);
  const float s = 127.0f / amn;
  i8x4 q;
  q[0] = (i8)fminf(fmaxf(rintf((v.x * r) * s), -128.f), 127.f);
  q[1] = (i8)fminf(fmaxf(rintf((v.y * r) * s), -128.f), 127.f);
  q[2] = (i8)fminf(fmaxf(rintf((v.z * r) * s), -128.f), 127.f);
  q[3] = (i8)fminf(fmaxf(rintf((v.w * r) * s), -128.f), 127.f);
  *(i8x4*)(xq + (long)t * DIMD + tid * 4) = q;
  if (tid == 0) sx[t] = amn * (1.0f / 127.0f);
}

// ---------------- router: 16 dots + noisy top-2 + gates + compaction ----------------
__global__ void k_router(const i8* __restrict__ xq, const float* __restrict__ sx,
                         const bf16* __restrict__ wrq, const bf16* __restrict__ wnq,
                         const float* __restrict__ eps, const float* __restrict__ wmean,
                         int* __restrict__ cnt, int* __restrict__ idx,
                         float* __restrict__ gate) {
  __shared__ float xf[DIMD];
  __shared__ float dots[16];
  const int t = blockIdx.x, tid = threadIdx.x;
  const i8* xr = xq + (long)t * DIMD;
  #pragma unroll
  for (int j = 0; j < 4; ++j) xf[tid * 4 + j] = (float)xr[tid * 4 + j];
  __syncthreads();
  const int grp = tid >> 4, l16 = tid & 15;
  const bf16* wv = (grp < 8) ? (wrq + grp * DIMD) : (wnq + (grp - 8) * DIMD);
  float s = 0.f;
  #pragma unroll
  for (int j = 0; j < 64; ++j) s += xf[l16 + j * 16] * (float)wv[l16 + j * 16];
  s += __shfl_xor(s, 1, 64); s += __shfl_xor(s, 2, 64);
  s += __shfl_xor(s, 4, 64); s += __shfl_xor(s, 8, 64);
  if (l16 == 0) dots[grp] = s;
  __syncthreads();
  if (tid == 0) {
    const float st = sx[t];
    const float fr = st * wmean[16], fn = st * wmean[17];
    float ny[8];
    #pragma unroll
    for (int e = 0; e < 8; ++e) {
      const float nl = dots[8 + e] * fn;
      const float sp = fmaxf(nl, 0.f) + log1pf(expf(-fabsf(nl)));
      ny[e] = dots[e] * fr + eps[t * 8 + e] * sp;
    }
    int i1 = 0;
    #pragma unroll
    for (int e = 1; e < 8; ++e) if (ny[e] > ny[i1]) i1 = e;
    int i2 = (i1 == 0) ? 1 : 0;
    #pragma unroll
    for (int e = 0; e < 8; ++e) if (e != i1 && ny[e] > ny[i2]) i2 = e;
    const float ex = expf(ny[i2] - ny[i1]);
    const float g1 = 1.0f / (1.0f + ex);
    const float g2 = ex * g1;
    int p1 = atomicAdd(&cnt[i1], 1);
    idx[i1 * CAP + p1] = t; gate[i1 * CAP + p1] = g1;
    int p2 = atomicAdd(&cnt[i2], 1);
    idx[i2 * CAP + p2] = t; gate[i2 * CAP + p2] = g2;
  }
}

__global__ void k_offsets(const int* __restrict__ cnt, int* __restrict__ offs) {
  if (threadIdx.x == 0) {
    int a = 0;
    for (int e = 0; e < NEXP; ++e) { offs[e] = a; a += cnt[e]; }
    offs[8] = a;
  }
}

// ---------------- i8 MFMA GEMM, 128x128 tile, BK=64, XOR-swizzled LDS ----------------
// mfma_i32_16x16x64_i8: bit-exact (int8-grid x ternary, i32 accum) — confirmed by
// R8 first-launch absmax == bf16 pipeline's exactly.
// Double-buffered, counted vmcnt (T3/T4), FENCED raw s_barrier; XCD decode (T1).
template <int KD, int LOGNT, bool L1>
__global__ __launch_bounds__(256, 4) void k_gemm(
    const i8* __restrict__ Abase, const i8* __restrict__ Wq,
    const int* __restrict__ cnt, const int* __restrict__ offs,
    const int* __restrict__ idx, const float* __restrict__ gate,
    const float* __restrict__ srow, const float* __restrict__ wmean,
    float* __restrict__ Out) {
  const int bid = blockIdx.x;
  const int xcd = bid & 7;
  const int s = bid >> 3;
  const int pl = s >> 5;                     // pair-local index within this XCD
  const int mt = s & 31;                     // mt fastest -> B-panel L2 reuse
  const int pidx = pl * 8 + xcd;             // bijective (e,nt) pair id
  const int e = pidx >> LOGNT;
  const int nt = pidx & ((1 << LOGNT) - 1);

  const int c = cnt[e];
  if (mt * 128 >= c) return;
  const int oe = offs[e];
  __shared__ __align__(16) char lds[33280];
  char* lA0 = lds;
  char* lB0 = lds + 8192;
  char* lA1 = lds + 16384;
  char* lB1 = lds + 24576;
  int* tokL = (int*)(lds + 32768);
  const int tid = threadIdx.x, w = tid >> 6, lam = tid & 63;
  if (tid < 128) {
    int i = mt * 128 + tid;
    tokL[tid] = idx[e * CAP + (i < c ? i : c - 1)];
  }
  __syncthreads();

  // staging sources: 512 16B-chunks per tile, 2 rounds x 256 threads.
  // LDS chunkId = row*4 + q (linear dest); global chunk c = q ^ ((row>>1)&3).
  const i8* aS[2];
  const i8* bS[2];
  #pragma unroll
  for (int i = 0; i < 2; ++i) {
    const int cid = w * 64 + lam + 256 * i;
    const int r = cid >> 2, q = cid & 3;
    const int cg = q ^ ((r >> 1) & 3);
    long arow;
    if (L1) arow = (long)tokL[r];
    else { int ii = mt * 128 + r; arow = (long)oe + (ii < c ? ii : c - 1); }
    aS[i] = Abase + arow * KD + cg * 16;
    bS[i] = Wq + (long)e * EXPSTRIDE + (long)(nt * 128 + r) * KD + cg * 16;
  }
  const int dbase = (w * 64 + lam) * 16;

  auto STAGE = [&](int kb, char* dA, char* dB) {
    #pragma unroll
    for (int i = 0; i < 2; ++i) gload16(aS[i] + kb * 64, dA + dbase + i * 4096);
    #pragma unroll
    for (int i = 0; i < 2; ++i) gload16(bS[i] + kb * 64, dB + dbase + i * 4096);
  };

  // fragment read offsets (swizzle-matched): lane reads 16B at row, chunk lam>>4
  const int wr = w >> 1, wc = w & 1;
  int offA[4], offB[4];
  const int cc = lam >> 4;
  #pragma unroll
  for (int m = 0; m < 4; ++m) {
    const int ra = wr * 64 + m * 16 + (lam & 15);
    const int rb = wc * 64 + m * 16 + (lam & 15);
    offA[m] = ra * 64 + ((cc ^ ((ra >> 1) & 3)) << 4);
    offB[m] = rb * 64 + ((cc ^ ((rb >> 1) & 3)) << 4);
  }
  i32x4 acc[4][4];
  #pragma unroll
  for (int m = 0; m < 4; ++m)
    #pragma unroll
    for (int n = 0; n < 4; ++n) acc[m][n] = (i32x4){0, 0, 0, 0};

  auto COMPUTE = [&](const char* cA, const char* cB) {
    i32x4 af[4], bfr[4];
    #pragma unroll
    for (int m = 0; m < 4; ++m) af[m] = *(const i32x4*)(cA + offA[m]);
    #pragma unroll
    for (int n = 0; n < 4; ++n) bfr[n] = *(const i32x4*)(cB + offB[n]);
    #pragma unroll
    for (int m = 0; m < 4; ++m)
      #pragma unroll
      for (int n = 0; n < 4; ++n)
        acc[m][n] = __builtin_amdgcn_mfma_i32_16x16x64_i8(af[m], bfr[n], acc[m][n], 0, 0, 0);
  };

  // K loop (KT even: 16 or 64): prefetch next tile; counted vmcnt keeps the
  // next tile's 4 loads in flight across barriers (never drain mid-loop).
  // Protocol: per-wave VMCNT(own loads) -> fenced barrier -> read = all waves'
  // loads visible; fenced barrier after COMPUTE -> safe to overwrite buffer.
  constexpr int KT = KD / 64;
  STAGE(0, lA0, lB0);
  for (int kb = 0; kb < KT; kb += 2) {
    STAGE(kb + 1, lA1, lB1);
    VMCNT4;                 // tile kb complete; tile kb+1 in flight
    BAR;
    COMPUTE(lA0, lB0);
    BAR;                    // all waves done reading buf0 -> safe to overwrite
    if (kb + 2 < KT) { STAGE(kb + 2, lA0, lB0); VMCNT4; } else { VMCNT0; }
    BAR;
    COMPUTE(lA1, lB1);
    BAR;
  }

  const float wm = wmean[(L1 ? 0 : 8) + e];
  #pragma unroll
  for (int m = 0; m < 4; ++m) {
    #pragma unroll
    for (int r = 0; r < 4; ++r) {
      const int rl = wr * 64 + m * 16 + ((lam >> 4) << 2) + r;
      const int i = mt * 128 + rl;
      if (i < c) {
        if (L1) {
          const float fac = srow[tokL[rl]] * wm;
          float* hp = Out + (long)(oe + i) * HIDN + nt * 128 + wc * 64 + (lam & 15);
          #pragma unroll
          for (int n = 0; n < 4; ++n) hp[n * 16] = fmaxf((float)acc[m][n][r] * fac, 0.f);
        } else {
          const float fac = srow[oe + i] * wm * gate[e * CAP + i];
          float* op = Out + (long)tokL[rl] * DIMD + nt * 128 + wc * 64 + (lam & 15);
          #pragma unroll
          for (int n = 0; n < 4; ++n) atomicAdd(op + n * 16, (float)acc[m][n][r] * fac);
        }
      }
    }
  }
}

// ---------------- h: rmsnorm + int8 quant (one block / assignment row) ----------------
__global__ void k_hquant(const float* __restrict__ h, i8* __restrict__ hq,
                         float* __restrict__ sh, const int* __restrict__ offs) {
  const int row = blockIdx.x;
  if (row >= offs[8]) return;
  const int tid = threadIdx.x;
  const f32x4* hr = (const f32x4*)(h + (long)row * HIDN);
  f32x4 v[4];
  float ss = 0.f, am = 0.f;
  #pragma unroll
  for (int j = 0; j < 4; ++j) {
    v[j] = hr[tid + j * 256];
    ss += v[j].x * v[j].x + v[j].y * v[j].y + v[j].z * v[j].z + v[j].w * v[j].w;
    am = fmaxf(am, fmaxf(fmaxf(fabsf(v[j].x), fabsf(v[j].y)),
                         fmaxf(fabsf(v[j].z), fabsf(v[j].w))));
  }
  #pragma unroll
  for (int o = 1; o < 64; o <<= 1) {
    ss += __shfl_xor(ss, o, 64);
    am = fmaxf(am, __shfl_xor(am, o, 64));
  }
  __shared__ float red[8];
  if ((tid & 63) == 0) { red[tid >> 6] = ss; red[4 + (tid >> 6)] = am; }
  __syncthreads();
  ss = red[0] + red[1] + red[2] + red[3];
  am = fmaxf(fmaxf(red[4], red[5]), fmaxf(red[6], red[7]));
  const float r = 1.0f / sqrtf(ss * (1.0f / HIDN) + 1e-6f);
  const float amn = fmaxf(am * r, 1e-5f);
  const float s = 127.0f / amn;
  i8* dst = hq + (long)row * HIDN;
  #pragma unroll
  for (int j = 0; j < 4; ++j) {
    i8x4 q;
    q[0] = (i8)fminf(fmaxf(rintf((v[j].x * r) * s), -128.f), 127.f);
    q[1] = (i8)fminf(fmaxf(rintf((v[j].y * r) * s), -128.f), 127.f);
    q[2] = (i8)fminf(fmaxf(rintf((v[j].z * r) * s), -128.f), 127.f);
    q[3] = (i8)fminf(fmaxf(rintf((v[j].w * r) * s), -128.f), 127.f);
    *(i8x4*)(dst + (tid + j * 256) * 4) = q;
  }
  if (tid == 0) sh[row] = amn * (1.0f / 127.0f);
}

extern "C" void kernel_launch(void* const* d_in, const int* in_sizes, int n_in,
                              void* d_out, int out_size, void* d_ws, size_t ws_size,
                              hipStream_t stream) {
  const float* x   = (const float*)d_in[0];
  const float* eps = (const float*)d_in[1];
  const float* wr  = (const float*)d_in[2];
  const float* wn  = (const float*)d_in[3];
  const float* w1  = (const float*)d_in[4];
  const float* w2  = (const float*)d_in[5];
  float* out = (float*)d_out;
  (void)in_sizes; (void)n_in; (void)ws_size;

  char* ws = (char*)d_ws;
  size_t off = 0;
  auto alloc = [&](size_t bytes) -> void* {
    void* p = ws + off;
    off = (off + bytes + 255) & ~(size_t)255;
    return p;
  };
  i8*    w1q      = (i8*)alloc(33554432);
  i8*    w2q      = (i8*)alloc(33554432);
  bf16*  wrq      = (bf16*)alloc(16384);
  bf16*  wnq      = (bf16*)alloc(16384);
  i8*    xq       = (i8*)alloc(4194304);
  float* sx       = (float*)alloc(16384);
  float* sh       = (float*)alloc(32768);
  int*   idxb     = (int*)alloc(131072);
  float* gateb    = (float*)alloc(131072);
  int*   cntb     = (int*)alloc(64);
  int*   offsb    = (int*)alloc(64);
  float* partials = (float*)alloc(8192);
  float* wmean    = (float*)alloc(128);
  float* h        = (float*)alloc(134217728);
  i8*    hq       = (i8*)alloc(33554432);

  (void)hipMemsetAsync(out, 0, (size_t)out_size * sizeof(float), stream);
  (void)hipMemsetAsync(cntb, 0, 64, stream);

  k_wsum<<<dim3(128, 16), 256, 0, stream>>>(w1, w2, partials);
  k_finalize<<<1, 256, 0, stream>>>(partials, wr, wn, wmean, wrq, wnq);
  k_wquant<<<32768, 256, 0, stream>>>(w1, w2, wmean, w1q, w2q);
  k_xquant<<<NTOK, 256, 0, stream>>>(x, xq, sx);
  k_router<<<NTOK, 256, 0, stream>>>(xq, sx, wrq, wnq, eps, wmean, cntb, idxb, gateb);
  k_offsets<<<1, 64, 0, stream>>>(cntb, offsb);
  k_gemm<1024, 5, true><<<8192, 256, 0, stream>>>(
      xq, w1q, cntb, offsb, idxb, gateb, sx, wmean, h);
  k_hquant<<<8192, 256, 0, stream>>>(h, hq, sh, offsb);
  k_gemm<4096, 3, false><<<2048, 256, 0, stream>>>(
      hq, w2q, cntb, offsb, idxb, gateb, sh, wmean, out);
}

// Round 10
// 650.612 us; speedup vs baseline: 1.2967x; 1.0164x over previous
//
#include <hip/hip_runtime.h>
#include <hip/hip_bf16.h>

#define DIMD 1024
#define NEXP 8
#define NTOK 4096
#define HIDN 4096
#define CAP  4096
#define EXPSTRIDE 4194304L  // HIDN*DIMD bytes per expert (i8)

typedef __bf16 bf16;
typedef bf16  bf16x8 __attribute__((ext_vector_type(8)));
typedef float f32x4  __attribute__((ext_vector_type(4)));
typedef int   i32x4  __attribute__((ext_vector_type(4)));
typedef signed char i8x8 __attribute__((ext_vector_type(8)));
typedef signed char i8x4 __attribute__((ext_vector_type(4)));
typedef signed char i8;

__device__ __forceinline__ void gload16(const void* g, void* l) {
  __builtin_amdgcn_global_load_lds(
      (const __attribute__((address_space(1))) unsigned int*)g,
      (__attribute__((address_space(3))) unsigned int*)l, 16, 0, 0);
}

#define VMCNT12 asm volatile("s_waitcnt vmcnt(12)" ::: "memory")
#define VMCNT8  asm volatile("s_waitcnt vmcnt(8)" ::: "memory")
#define VMCNT4  asm volatile("s_waitcnt vmcnt(4)" ::: "memory")
#define VMCNT0  asm volatile("s_waitcnt vmcnt(0)" ::: "memory")
// Raw s_barrier WITH compiler memory fence (R9-verified: builtin alone races —
// LLVM hoists LDS reads above it; the asm memory clobber pins them).
#define BAR    asm volatile("s_barrier" ::: "memory")

// ---------------- weight |w| partial sums: grid (128, 16) ----------------
__global__ void k_wsum(const float* __restrict__ w1, const float* __restrict__ w2,
                       float* __restrict__ partials) {
  const int slot = blockIdx.y;   // 0-7: w1 expert, 8-15: w2 expert
  const int b = blockIdx.x;
  const int tid = threadIdx.x;
  const float* src = (slot < 8) ? (w1 + (long)slot * EXPSTRIDE)
                                : (w2 + (long)(slot - 8) * EXPSTRIDE);
  const f32x4* p = (const f32x4*)src;
  float s = 0.f;
  #pragma unroll
  for (int j = 0; j < 32; ++j) {
    f32x4 v = p[(long)b * 8192 + j * 256 + tid];
    s += fabsf(v.x) + fabsf(v.y) + fabsf(v.z) + fabsf(v.w);
  }
  #pragma unroll
  for (int o = 1; o < 64; o <<= 1) s += __shfl_xor(s, o, 64);
  __shared__ float red[4];
  if ((tid & 63) == 0) red[tid >> 6] = s;
  __syncthreads();
  if (tid == 0) partials[slot * 128 + b] = red[0] + red[1] + red[2] + red[3];
}

// ---------------- finalize scales + quantize router weights ----------------
__global__ void k_finalize(const float* __restrict__ partials,
                           const float* __restrict__ wr, const float* __restrict__ wn,
                           float* __restrict__ wmean,
                           bf16* __restrict__ wrq, bf16* __restrict__ wnq) {
  const int tid = threadIdx.x;
  if (tid < 16) {  // deterministic serial sum of 128 partials per tensor
    float s = 0.f;
    for (int j = 0; j < 128; ++j) s += partials[tid * 128 + j];
    wmean[tid] = fmaxf(s * (1.0f / 4194304.0f), 1e-5f);
  }
  float sr = 0.f, sn = 0.f;
  #pragma unroll
  for (int j = 0; j < 32; ++j) {
    sr += fabsf(wr[j * 256 + tid]);
    sn += fabsf(wn[j * 256 + tid]);
  }
  #pragma unroll
  for (int o = 1; o < 64; o <<= 1) {
    sr += __shfl_xor(sr, o, 64);
    sn += __shfl_xor(sn, o, 64);
  }
  __shared__ float red[8];
  if ((tid & 63) == 0) { red[tid >> 6] = sr; red[4 + (tid >> 6)] = sn; }
  __syncthreads();
  if (tid == 0) {
    wmean[16] = fmaxf((red[0] + red[1] + red[2] + red[3]) * (1.0f / 8192.0f), 1e-5f);
    wmean[17] = fmaxf((red[4] + red[5] + red[6] + red[7]) * (1.0f / 8192.0f), 1e-5f);
  }
  __syncthreads();
  const float ir = 1.0f / wmean[16];
  const float in = 1.0f / wmean[17];
  for (int j = 0; j < 32; ++j) {
    int i = j * 256 + tid;
    wrq[i] = (bf16)fminf(fmaxf(rintf(wr[i] * ir), -1.f), 1.f);
    wnq[i] = (bf16)fminf(fmaxf(rintf(wn[i] * in), -1.f), 1.f);
  }
}

// ---------------- ternary-quantize w1/w2 -> i8 {-1,0,1}: grid 32768 ----------------
__global__ void k_wquant(const float* __restrict__ w1, const float* __restrict__ w2,
                         const float* __restrict__ wmean,
                         i8* __restrict__ w1q, i8* __restrict__ w2q) {
  const int tid = threadIdx.x;
  const int which = blockIdx.x >> 14;                       // 0: w1, 1: w2
  const long lg = (long)(blockIdx.x & 16383) * 256 + tid;   // 8-elem group id
  const int e = (int)(lg >> 19);                            // 524288 groups / expert
  const float inv = 1.0f / wmean[(which ? 8 : 0) + e];
  const float* src = which ? w2 : w1;
  i8* dst = which ? w2q : w1q;
  const f32x4* p = (const f32x4*)src + lg * 2;
  f32x4 v0 = p[0], v1 = p[1];
  i8x8 q;
  q[0] = (i8)fminf(fmaxf(rintf(v0.x * inv), -1.f), 1.f);
  q[1] = (i8)fminf(fmaxf(rintf(v0.y * inv), -1.f), 1.f);
  q[2] = (i8)fminf(fmaxf(rintf(v0.z * inv), -1.f), 1.f);
  q[3] = (i8)fminf(fmaxf(rintf(v0.w * inv), -1.f), 1.f);
  q[4] = (i8)fminf(fmaxf(rintf(v1.x * inv), -1.f), 1.f);
  q[5] = (i8)fminf(fmaxf(rintf(v1.y * inv), -1.f), 1.f);
  q[6] = (i8)fminf(fmaxf(rintf(v1.z * inv), -1.f), 1.f);
  q[7] = (i8)fminf(fmaxf(rintf(v1.w * inv), -1.f), 1.f);
  *(i8x8*)(dst + lg * 8) = q;
}

// ---------------- x: rmsnorm + int8 quant (one block / token) ----------------
__global__ void k_xquant(const float* __restrict__ x, i8* __restrict__ xq,
                         float* __restrict__ sx) {
  const int t = blockIdx.x, tid = threadIdx.x;
  f32x4 v = ((const f32x4*)(x + (long)t * DIMD))[tid];
  float ss = v.x * v.x + v.y * v.y + v.z * v.z + v.w * v.w;
  float am = fmaxf(fmaxf(fabsf(v.x), fabsf(v.y)), fmaxf(fabsf(v.z), fabsf(v.w)));
  #pragma unroll
  for (int o = 1; o < 64; o <<= 1) {
    ss += __shfl_xor(ss, o, 64);
    am = fmaxf(am, __shfl_xor(am, o, 64));
  }
  __shared__ float red[8];
  if ((tid & 63) == 0) { red[tid >> 6] = ss; red[4 + (tid >> 6)] = am; }
  __syncthreads();
  ss = red[0] + red[1] + red[2] + red[3];
  am = fmaxf(fmaxf(red[4], red[5]), fmaxf(red[6], red[7]));
  const float r = 1.0f / sqrtf(ss * (1.0f / DIMD) + 1e-6f);
  const float amn = fmaxf(am * r, 1e-5f);
  const float s = 127.0f / amn;
  i8x4 q;
  q[0] = (i8)fminf(fmaxf(rintf((v.x * r) * s), -128.f), 127.f);
  q[1] = (i8)fminf(fmaxf(rintf((v.y * r) * s), -128.f), 127.f);
  q[2] = (i8)fminf(fmaxf(rintf((v.z * r) * s), -128.f), 127.f);
  q[3] = (i8)fminf(fmaxf(rintf((v.w * r) * s), -128.f), 127.f);
  *(i8x4*)(xq + (long)t * DIMD + tid * 4) = q;
  if (tid == 0) sx[t] = amn * (1.0f / 127.0f);
}

// ---------------- router: 16 dots + noisy top-2 + gates + compaction ----------------
__global__ void k_router(const i8* __restrict__ xq, const float* __restrict__ sx,
                         const bf16* __restrict__ wrq, const bf16* __restrict__ wnq,
                         const float* __restrict__ eps, const float* __restrict__ wmean,
                         int* __restrict__ cnt, int* __restrict__ idx,
                         float* __restrict__ gate) {
  __shared__ float xf[DIMD];
  __shared__ float dots[16];
  const int t = blockIdx.x, tid = threadIdx.x;
  const i8* xr = xq + (long)t * DIMD;
  #pragma unroll
  for (int j = 0; j < 4; ++j) xf[tid * 4 + j] = (float)xr[tid * 4 + j];
  __syncthreads();
  const int grp = tid >> 4, l16 = tid & 15;
  const bf16* wv = (grp < 8) ? (wrq + grp * DIMD) : (wnq + (grp - 8) * DIMD);
  float s = 0.f;
  #pragma unroll
  for (int j = 0; j < 64; ++j) s += xf[l16 + j * 16] * (float)wv[l16 + j * 16];
  s += __shfl_xor(s, 1, 64); s += __shfl_xor(s, 2, 64);
  s += __shfl_xor(s, 4, 64); s += __shfl_xor(s, 8, 64);
  if (l16 == 0) dots[grp] = s;
  __syncthreads();
  if (tid == 0) {
    const float st = sx[t];
    const float fr = st * wmean[16], fn = st * wmean[17];
    float ny[8];
    #pragma unroll
    for (int e = 0; e < 8; ++e) {
      const float nl = dots[8 + e] * fn;
      const float sp = fmaxf(nl, 0.f) + log1pf(expf(-fabsf(nl)));
      ny[e] = dots[e] * fr + eps[t * 8 + e] * sp;
    }
    int i1 = 0;
    #pragma unroll
    for (int e = 1; e < 8; ++e) if (ny[e] > ny[i1]) i1 = e;
    int i2 = (i1 == 0) ? 1 : 0;
    #pragma unroll
    for (int e = 0; e < 8; ++e) if (e != i1 && ny[e] > ny[i2]) i2 = e;
    const float ex = expf(ny[i2] - ny[i1]);
    const float g1 = 1.0f / (1.0f + ex);
    const float g2 = ex * g1;
    int p1 = atomicAdd(&cnt[i1], 1);
    idx[i1 * CAP + p1] = t; gate[i1 * CAP + p1] = g1;
    int p2 = atomicAdd(&cnt[i2], 1);
    idx[i2 * CAP + p2] = t; gate[i2 * CAP + p2] = g2;
  }
}

__global__ void k_offsets(const int* __restrict__ cnt, int* __restrict__ offs) {
  if (threadIdx.x == 0) {
    int a = 0;
    for (int e = 0; e < NEXP; ++e) { offs[e] = a; a += cnt[e]; }
    offs[8] = a;
  }
}

// ---------------- i8 MFMA GEMM, 128x128 tile, BK=64, XOR-swizzled LDS ----------------
// L1 (KD=1024): 2-buffer depth-1 pipeline, 4 blocks/CU (R9-verified).
// L2 (KD=4096): 4-buffer ring, prefetch 3 tiles ahead (vmcnt(12) steady state) —
//   R9 PMC showed L2 phase stall ~1400cyc = HBM latency minus 1-phase cover;
//   3-phase cover (~1650cyc) should eliminate it. 2 blocks/CU (= its active work).
template <int KD, int LOGNT, bool L1>
__global__ __launch_bounds__(256, L1 ? 4 : 2) void k_gemm(
    const i8* __restrict__ Abase, const i8* __restrict__ Wq,
    const int* __restrict__ cnt, const int* __restrict__ offs,
    const int* __restrict__ idx, const float* __restrict__ gate,
    const float* __restrict__ srow, const float* __restrict__ wmean,
    float* __restrict__ Out) {
  const int bid = blockIdx.x;
  const int xcd = bid & 7;
  const int s = bid >> 3;
  const int pl = s >> 5;                     // pair-local index within this XCD
  const int mt = s & 31;                     // mt fastest -> B-panel L2 reuse
  const int pidx = pl * 8 + xcd;             // bijective (e,nt) pair id
  const int e = pidx >> LOGNT;
  const int nt = pidx & ((1 << LOGNT) - 1);

  const int c = cnt[e];
  if (mt * 128 >= c) return;
  const int oe = offs[e];
  constexpr int NBUF = L1 ? 2 : 4;
  __shared__ __align__(16) char lds[NBUF * 16384 + 512];
  int* tokL = (int*)(lds + NBUF * 16384);
  const int tid = threadIdx.x, w = tid >> 6, lam = tid & 63;
  if (tid < 128) {
    int i = mt * 128 + tid;
    tokL[tid] = idx[e * CAP + (i < c ? i : c - 1)];
  }
  __syncthreads();

  // staging sources: 512 16B-chunks per tile, 2 rounds x 256 threads.
  // LDS chunkId = row*4 + q (linear dest); global chunk cg = q ^ ((row>>1)&3).
  const i8* aS[2];
  const i8* bS[2];
  #pragma unroll
  for (int i = 0; i < 2; ++i) {
    const int cid = w * 64 + lam + 256 * i;
    const int r = cid >> 2, q = cid & 3;
    const int cg = q ^ ((r >> 1) & 3);
    long arow;
    if (L1) arow = (long)tokL[r];
    else { int ii = mt * 128 + r; arow = (long)oe + (ii < c ? ii : c - 1); }
    aS[i] = Abase + arow * KD + cg * 16;
    bS[i] = Wq + (long)e * EXPSTRIDE + (long)(nt * 128 + r) * KD + cg * 16;
  }
  const int dbase = (w * 64 + lam) * 16;

  auto STAGE = [&](int kb, char* dA, char* dB) {
    #pragma unroll
    for (int i = 0; i < 2; ++i) gload16(aS[i] + kb * 64, dA + dbase + i * 4096);
    #pragma unroll
    for (int i = 0; i < 2; ++i) gload16(bS[i] + kb * 64, dB + dbase + i * 4096);
  };

  // fragment read offsets (swizzle-matched): lane reads 16B at row, chunk lam>>4
  const int wr = w >> 1, wc = w & 1;
  int offA[4], offB[4];
  const int cc = lam >> 4;
  #pragma unroll
  for (int m = 0; m < 4; ++m) {
    const int ra = wr * 64 + m * 16 + (lam & 15);
    const int rb = wc * 64 + m * 16 + (lam & 15);
    offA[m] = ra * 64 + ((cc ^ ((ra >> 1) & 3)) << 4);
    offB[m] = rb * 64 + ((cc ^ ((rb >> 1) & 3)) << 4);
  }
  i32x4 acc[4][4];
  #pragma unroll
  for (int m = 0; m < 4; ++m)
    #pragma unroll
    for (int n = 0; n < 4; ++n) acc[m][n] = (i32x4){0, 0, 0, 0};

  auto COMPUTE = [&](const char* cA, const char* cB) {
    i32x4 af[4], bfr[4];
    #pragma unroll
    for (int m = 0; m < 4; ++m) af[m] = *(const i32x4*)(cA + offA[m]);
    #pragma unroll
    for (int n = 0; n < 4; ++n) bfr[n] = *(const i32x4*)(cB + offB[n]);
    #pragma unroll
    for (int m = 0; m < 4; ++m)
      #pragma unroll
      for (int n = 0; n < 4; ++n)
        acc[m][n] = __builtin_amdgcn_mfma_i32_16x16x64_i8(af[m], bfr[n], acc[m][n], 0, 0, 0);
  };

  constexpr int KT = KD / 64;
  if constexpr (L1) {
    // depth-1: prefetch 1 tile; vmcnt(4) keeps it in flight across barriers.
    char* lA0 = lds;            char* lB0 = lds + 8192;
    char* lA1 = lds + 16384;    char* lB1 = lds + 24576;
    STAGE(0, lA0, lB0);
    for (int kb = 0; kb < KT; kb += 2) {
      STAGE(kb + 1, lA1, lB1);
      VMCNT4;
      BAR;
      COMPUTE(lA0, lB0);
      BAR;
      if (kb + 2 < KT) { STAGE(kb + 2, lA0, lB0); VMCNT4; } else { VMCNT0; }
      BAR;
      COMPUTE(lA1, lB1);
      BAR;
    }
  } else {
    // depth-3: 4-buffer ring; steady-state 16 loads in flight, wait vmcnt(12)
    // = exactly the oldest tile's 4 loads (m218 counted-vmcnt ledger).
    char* bA[4]; char* bB[4];
    #pragma unroll
    for (int i = 0; i < 4; ++i) { bA[i] = lds + i * 16384; bB[i] = lds + i * 16384 + 8192; }
    STAGE(0, bA[0], bB[0]);
    STAGE(1, bA[1], bB[1]);
    STAGE(2, bA[2], bB[2]);      // 12 outstanding
    int kb = 0;
    for (; kb + 4 < KT; kb += 4) {
      #pragma unroll
      for (int p = 0; p < 4; ++p) {
        STAGE(kb + 3 + p, bA[(p + 3) & 3], bB[(p + 3) & 3]);  // 16 in flight
        VMCNT12;                  // oldest tile (kb+p) landed
        BAR;
        COMPUTE(bA[p], bB[p]);
        BAR;                      // all waves done -> buffer reusable
      }
    }
    // kb == KT-4: B0..B2 hold tiles kb..kb+2; stage last, drain 12->8->4->0.
    STAGE(KT - 1, bA[3], bB[3]);
    VMCNT12; BAR; COMPUTE(bA[0], bB[0]); BAR;
    VMCNT8;  BAR; COMPUTE(bA[1], bB[1]); BAR;
    VMCNT4;  BAR; COMPUTE(bA[2], bB[2]); BAR;
    VMCNT0;  BAR; COMPUTE(bA[3], bB[3]);
  }

  const float wm = wmean[(L1 ? 0 : 8) + e];
  #pragma unroll
  for (int m = 0; m < 4; ++m) {
    #pragma unroll
    for (int r = 0; r < 4; ++r) {
      const int rl = wr * 64 + m * 16 + ((lam >> 4) << 2) + r;
      const int i = mt * 128 + rl;
      if (i < c) {
        if (L1) {
          const float fac = srow[tokL[rl]] * wm;
          float* hp = Out + (long)(oe + i) * HIDN + nt * 128 + wc * 64 + (lam & 15);
          #pragma unroll
          for (int n = 0; n < 4; ++n) hp[n * 16] = fmaxf((float)acc[m][n][r] * fac, 0.f);
        } else {
          const float fac = srow[oe + i] * wm * gate[e * CAP + i];
          float* op = Out + (long)tokL[rl] * DIMD + nt * 128 + wc * 64 + (lam & 15);
          #pragma unroll
          for (int n = 0; n < 4; ++n) atomicAdd(op + n * 16, (float)acc[m][n][r] * fac);
        }
      }
    }
  }
}

// ---------------- h: rmsnorm + int8 quant (one block / assignment row) ----------------
__global__ void k_hquant(const float* __restrict__ h, i8* __restrict__ hq,
                         float* __restrict__ sh, const int* __restrict__ offs) {
  const int row = blockIdx.x;
  if (row >= offs[8]) return;
  const int tid = threadIdx.x;
  const f32x4* hr = (const f32x4*)(h + (long)row * HIDN);
  f32x4 v[4];
  float ss = 0.f, am = 0.f;
  #pragma unroll
  for (int j = 0; j < 4; ++j) {
    v[j] = hr[tid + j * 256];
    ss += v[j].x * v[j].x + v[j].y * v[j].y + v[j].z * v[j].z + v[j].w * v[j].w;
    am = fmaxf(am, fmaxf(fmaxf(fabsf(v[j].x), fabsf(v[j].y)),
                         fmaxf(fabsf(v[j].z), fabsf(v[j].w))));
  }
  #pragma unroll
  for (int o = 1; o < 64; o <<= 1) {
    ss += __shfl_xor(ss, o, 64);
    am = fmaxf(am, __shfl_xor(am, o, 64));
  }
  __shared__ float red[8];
  if ((tid & 63) == 0) { red[tid >> 6] = ss; red[4 + (tid >> 6)] = am; }
  __syncthreads();
  ss = red[0] + red[1] + red[2] + red[3];
  am = fmaxf(fmaxf(red[4], red[5]), fmaxf(red[6], red[7]));
  const float r = 1.0f / sqrtf(ss * (1.0f / HIDN) + 1e-6f);
  const float amn = fmaxf(am * r, 1e-5f);
  const float s = 127.0f / amn;
  i8* dst = hq + (long)row * HIDN;
  #pragma unroll
  for (int j = 0; j < 4; ++j) {
    i8x4 q;
    q[0] = (i8)fminf(fmaxf(rintf((v[j].x * r) * s), -128.f), 127.f);
    q[1] = (i8)fminf(fmaxf(rintf((v[j].y * r) * s), -128.f), 127.f);
    q[2] = (i8)fminf(fmaxf(rintf((v[j].z * r) * s), -128.f), 127.f);
    q[3] = (i8)fminf(fmaxf(rintf((v[j].w * r) * s), -128.f), 127.f);
    *(i8x4*)(dst + (tid + j * 256) * 4) = q;
  }
  if (tid == 0) sh[row] = amn * (1.0f / 127.0f);
}

extern "C" void kernel_launch(void* const* d_in, const int* in_sizes, int n_in,
                              void* d_out, int out_size, void* d_ws, size_t ws_size,
                              hipStream_t stream) {
  const float* x   = (const float*)d_in[0];
  const float* eps = (const float*)d_in[1];
  const float* wr  = (const float*)d_in[2];
  const float* wn  = (const float*)d_in[3];
  const float* w1  = (const float*)d_in[4];
  const float* w2  = (const float*)d_in[5];
  float* out = (float*)d_out;
  (void)in_sizes; (void)n_in; (void)ws_size;

  char* ws = (char*)d_ws;
  size_t off = 0;
  auto alloc = [&](size_t bytes) -> void* {
    void* p = ws + off;
    off = (off + bytes + 255) & ~(size_t)255;
    return p;
  };
  i8*    w1q      = (i8*)alloc(33554432);
  i8*    w2q      = (i8*)alloc(33554432);
  bf16*  wrq      = (bf16*)alloc(16384);
  bf16*  wnq      = (bf16*)alloc(16384);
  i8*    xq       = (i8*)alloc(4194304);
  float* sx       = (float*)alloc(16384);
  float* sh       = (float*)alloc(32768);
  int*   idxb     = (int*)alloc(131072);
  float* gateb    = (float*)alloc(131072);
  int*   cntb     = (int*)alloc(64);
  int*   offsb    = (int*)alloc(64);
  float* partials = (float*)alloc(8192);
  float* wmean    = (float*)alloc(128);
  float* h        = (float*)alloc(134217728);
  i8*    hq       = (i8*)alloc(33554432);

  (void)hipMemsetAsync(out, 0, (size_t)out_size * sizeof(float), stream);
  (void)hipMemsetAsync(cntb, 0, 64, stream);

  k_wsum<<<dim3(128, 16), 256, 0, stream>>>(w1, w2, partials);
  k_finalize<<<1, 256, 0, stream>>>(partials, wr, wn, wmean, wrq, wnq);
  k_wquant<<<32768, 256, 0, stream>>>(w1, w2, wmean, w1q, w2q);
  k_xquant<<<NTOK, 256, 0, stream>>>(x, xq, sx);
  k_router<<<NTOK, 256, 0, stream>>>(xq, sx, wrq, wnq, eps, wmean, cntb, idxb, gateb);
  k_offsets<<<1, 64, 0, stream>>>(cntb, offsb);
  k_gemm<1024, 5, true><<<8192, 256, 0, stream>>>(
      xq, w1q, cntb, offsb, idxb, gateb, sx, wmean, h);
  k_hquant<<<8192, 256, 0, stream>>>(h, hq, sh, offsb);
  k_gemm<4096, 3, false><<<2048, 256, 0, stream>>>(
      hq, w2q, cntb, offsb, idxb, gateb, sh, wmean, out);
}